// Round 4
// baseline (381.787 us; speedup 1.0000x reference)
//
#include <hip/hip_runtime.h>

#define CIN  32
#define COUT 64
#define PP   1024
#define NN   24
#define NA   60
#define KS   4
#define PA   (PP*NA)          // 61440
#define CK   (CIN*KS)         // 128
#define MPAD (PP*64)          // 65536 padded (p,a) rows
constexpr float SIGMA_INV = 12.5f;   // 1/0.08
constexpr float EPS = 1e-5f;

typedef __attribute__((ext_vector_type(8))) short short8;
typedef __attribute__((ext_vector_type(4))) float floatx4;

__device__ inline unsigned short f2bf(float f) {   // RTNE
    unsigned u = __float_as_uint(f);
    return (unsigned short)((u + 0x7fffu + ((u >> 16) & 1u)) >> 16);
}

// ---------------- k0: transpose feats [CIN,P,NA] -> ft [P,NA,CIN] ----------------
__global__ __launch_bounds__(256) void k0_transpose(
    const float* __restrict__ feats, float* __restrict__ ft)
{
    int p = blockIdx.x;
    for (int i = threadIdx.x; i < CIN*NA; i += 256) {
        int c = i / NA, a = i - c*NA;
        ft[((size_t)p*NA + a)*CIN + c] = feats[(size_t)c*PA + (size_t)p*NA + a];
    }
}

// ---------------- k0b: W fp32 -> bf16 ----------------
__global__ __launch_bounds__(256) void k0b_cvtW(
    const float* __restrict__ W, unsigned short* __restrict__ Wb)
{
    int i = blockIdx.x * 256 + threadIdx.x;
    if (i < COUT*CK) Wb[i] = f2bf(W[i]);
}

// ---------------- kA: gather + kernel-weight conv -> fkb [MPAD, CK] bf16 ----------------
__global__ __launch_bounds__(256, 4) void kA_fk(
    const float* __restrict__ xyz,       // [3,P]
    const float* __restrict__ ft,        // [P,NA,CIN]
    const int*   __restrict__ inter_idx, // [P,NN]
    const float* __restrict__ anchors,   // [NA,3,3]
    const float* __restrict__ kern,      // [KS,3]
    unsigned short* __restrict__ fkb)    // [MPAD, CK] bf16
{
    const int p   = blockIdx.x;
    const int tid = threadIdx.x;
    const int g   = tid >> 6;            // channel group 0..3 (8 ch each)
    const int l   = tid & 63;
    const bool valid = (l < NA);
    const int  a     = valid ? l : (NA - 1);

    __shared__ float4 s_rel[NN];
    __shared__ int    s_idx[NN];

    if (tid < NN) {
        int j = inter_idx[p*NN + tid];
        s_idx[tid] = j;
        float rx = xyz[j]        - xyz[p];
        float ry = xyz[PP + j]   - xyz[PP + p];
        float rz = xyz[2*PP + j] - xyz[2*PP + p];
        s_rel[tid] = make_float4(rx, ry, rz, rx*rx + ry*ry + rz*rz);
    }

    float Cw[KS], Rx[KS], Ry[KS], Rz[KS];
    {
        const float* A = anchors + a*9;
        float a00=A[0],a01=A[1],a02=A[2],a10=A[3],a11=A[4],a12=A[5],a20=A[6],a21=A[7],a22=A[8];
        #pragma unroll
        for (int k = 0; k < KS; ++k) {
            float kx = kern[k*3+0], ky = kern[k*3+1], kz = kern[k*3+2];
            float r0 = a00*kx + a01*ky + a02*kz;
            float r1 = a10*kx + a11*ky + a12*kz;
            float r2 = a20*kx + a21*ky + a22*kz;
            Cw[k] = 1.0f - SIGMA_INV*(r0*r0 + r1*r1 + r2*r2);
            Rx[k] = 2.0f*SIGMA_INV*r0;
            Ry[k] = 2.0f*SIGMA_INV*r1;
            Rz[k] = 2.0f*SIGMA_INV*r2;
        }
    }
    __syncthreads();

    float acc[8][KS];
    #pragma unroll
    for (int c = 0; c < 8; ++c)
        #pragma unroll
        for (int k = 0; k < KS; ++k) acc[c][k] = 0.0f;

    #pragma unroll
    for (int n = 0; n < NN; ++n) {
        float4 rel = s_rel[n];
        int j = s_idx[n];
        const float* fp = ft + ((size_t)j*NA + a)*CIN + g*8;
        float4 f0 = *(const float4*)(fp);
        float4 f1 = *(const float4*)(fp + 4);
        float tb = -SIGMA_INV * rel.w;
        float w[KS];
        #pragma unroll
        for (int k = 0; k < KS; ++k) {
            float v = Cw[k] + tb;
            v = fmaf(rel.x, Rx[k], v);
            v = fmaf(rel.y, Ry[k], v);
            v = fmaf(rel.z, Rz[k], v);
            w[k] = v > 0.0f ? v : 0.0f;
        }
        float f[8] = {f0.x,f0.y,f0.z,f0.w,f1.x,f1.y,f1.z,f1.w};
        #pragma unroll
        for (int c = 0; c < 8; ++c)
            #pragma unroll
            for (int k = 0; k < KS; ++k)
                acc[c][k] = fmaf(f[c], w[k], acc[c][k]);
    }

    // pack 32 bf16 (ck = (g*8+c)*4+k local col c*4+k), row m = p*64 + l; rows l>=60 = zeros
    unsigned pk[16];
    #pragma unroll
    for (int c = 0; c < 8; ++c) {
        #pragma unroll
        for (int k = 0; k < 4; k += 2) {
            float v0 = valid ? acc[c][k]   : 0.0f;
            float v1 = valid ? acc[c][k+1] : 0.0f;
            pk[(c*4+k) >> 1] = (unsigned)f2bf(v0) | ((unsigned)f2bf(v1) << 16);
        }
    }
    unsigned short* row = fkb + ((size_t)(p*64 + l))*CK + g*32;
    uint4* r4 = (uint4*)row;
    r4[0] = make_uint4(pk[0], pk[1], pk[2], pk[3]);
    r4[1] = make_uint4(pk[4], pk[5], pk[6], pk[7]);
    r4[2] = make_uint4(pk[8], pk[9], pk[10], pk[11]);
    r4[3] = make_uint4(pk[12], pk[13], pk[14], pk[15]);
}

// ---------------- kB: MFMA GEMM C[d,m] = W[d,ck]*fk[m,ck] + per-block stats ----------------
__global__ __launch_bounds__(256) void kB_gemm(
    const unsigned short* __restrict__ fkb,  // [MPAD, CK]
    const unsigned short* __restrict__ Wb,   // [COUT, CK]
    float* __restrict__ out,                 // [COUT, PA]  pre-norm, unpadded
    float* __restrict__ psum,                // [COUT, 1024 blocks]
    float* __restrict__ psq)
{
    const int tid    = threadIdx.x;
    const int w      = tid >> 6;      // wave -> d-tile
    const int l      = tid & 63;
    const int lane15 = l & 15;
    const int quad   = l >> 4;
    const int m0     = blockIdx.x * 64;   // 64 padded m-rows per block
    const int d0     = w * 16;

    floatx4 acc[4];
    #pragma unroll
    for (int t = 0; t < 4; ++t) acc[t] = (floatx4){0.f,0.f,0.f,0.f};

    #pragma unroll
    for (int ks = 0; ks < 4; ++ks) {
        short8 afrag = *(const short8*)(Wb + (d0 + lane15)*CK + ks*32 + quad*8);
        #pragma unroll
        for (int t = 0; t < 4; ++t) {
            short8 bfrag = *(const short8*)(fkb + (size_t)(m0 + t*16 + lane15)*CK + ks*32 + quad*8);
            acc[t] = __builtin_amdgcn_mfma_f32_16x16x32_bf16(afrag, bfrag, acc[t], 0, 0, 0);
        }
    }

    // C[d = d0+quad*4+r][m = m0 + t*16 + lane15]; valid iff (m & 63) < 60
    float s[4] = {0.f,0.f,0.f,0.f}, q[4] = {0.f,0.f,0.f,0.f};
    const int p = m0 >> 6;   // all 64 rows of this block share one p
    #pragma unroll
    for (int t = 0; t < 4; ++t) {
        int acol = t*16 + lane15;            // a in 0..63
        bool vcol = acol < NA;
        #pragma unroll
        for (int r = 0; r < 4; ++r) {
            float v = acc[t][r];
            int d = d0 + quad*4 + r;
            if (vcol) out[(size_t)d*PA + (size_t)p*NA + acol] = v;
            s[r] += v;  q[r] += v*v;         // padded cols are exact zeros
        }
    }
    #pragma unroll
    for (int r = 0; r < 4; ++r) {
        float ss = s[r], qq = q[r];
        #pragma unroll
        for (int off = 8; off; off >>= 1) {
            ss += __shfl_down(ss, off, 16);
            qq += __shfl_down(qq, off, 16);
        }
        if (lane15 == 0) {
            int d = d0 + quad*4 + r;
            psum[d*PP + blockIdx.x] = ss;
            psq [d*PP + blockIdx.x] = qq;
        }
    }
}

// ---------------- k2: per-channel mean / rsqrt(var) ----------------
__global__ __launch_bounds__(256) void k2_stats(
    const float* __restrict__ psum, const float* __restrict__ psq,
    float* __restrict__ stats)
{
    int d = blockIdx.x, tid = threadIdx.x;
    float s = 0.f, q = 0.f;
    for (int t = tid; t < PP; t += 256) {
        s += psum[d*PP + t];
        q += psq [d*PP + t];
    }
    #pragma unroll
    for (int off = 32; off; off >>= 1) {
        s += __shfl_down(s, off, 64);
        q += __shfl_down(q, off, 64);
    }
    __shared__ float ss[4], sq[4];
    int w = tid >> 6;
    if ((tid & 63) == 0) { ss[w] = s; sq[w] = q; }
    __syncthreads();
    if (tid == 0) {
        float S = ss[0]+ss[1]+ss[2]+ss[3];
        float Q = sq[0]+sq[1]+sq[2]+sq[3];
        const float inv = 1.0f / (float)PA;
        float mu  = S * inv;
        float var = Q * inv - mu*mu;
        stats[d]        = mu;
        stats[COUT + d] = rsqrtf(var + EPS);
    }
}

// ---------------- k3: normalize + relu in place (float4) ----------------
__global__ __launch_bounds__(256) void k3_norm(
    float* __restrict__ out, const float* __restrict__ stats)
{
    int d = blockIdx.y;
    int i = (blockIdx.x * 256 + threadIdx.x) * 4;   // PA % 1024 == 0
    float mu = stats[d], rs = stats[COUT + d];
    float4* po = (float4*)(out + (size_t)d*PA + i);
    float4 v = *po;
    v.x = fmaxf((v.x - mu)*rs, 0.f);
    v.y = fmaxf((v.y - mu)*rs, 0.f);
    v.z = fmaxf((v.z - mu)*rs, 0.f);
    v.w = fmaxf((v.w - mu)*rs, 0.f);
    *po = v;
}

extern "C" void kernel_launch(void* const* d_in, const int* in_sizes, int n_in,
                              void* d_out, int out_size, void* d_ws, size_t ws_size,
                              hipStream_t stream) {
    const float* xyz     = (const float*)d_in[0];
    const float* feats   = (const float*)d_in[1];
    const int*   idx     = (const int*)d_in[2];
    const float* anchors = (const float*)d_in[3];
    const float* kern    = (const float*)d_in[4];
    const float* W       = (const float*)d_in[5];
    float* out = (float*)d_out;

    float* ws = (float*)d_ws;
    float*          ft    = ws;                               // 1,966,080 f
    unsigned short* fkb   = (unsigned short*)(ft + (size_t)PP*NA*CIN);  // 8,388,608 us = 16.8MB
    unsigned short* Wb    = fkb + (size_t)MPAD*CK;            // 8192 us
    float*          psum  = (float*)(Wb + COUT*CK);           // 65,536 f
    float*          psq   = psum + COUT*PP;                   // 65,536 f
    float*          stats = psq  + COUT*PP;                   // 128 f

    hipLaunchKernelGGL(k0_transpose, dim3(PP), dim3(256), 0, stream, feats, ft);
    hipLaunchKernelGGL(k0b_cvtW, dim3((COUT*CK + 255)/256), dim3(256), 0, stream, W, Wb);
    hipLaunchKernelGGL(kA_fk, dim3(PP), dim3(256), 0, stream,
                       xyz, ft, idx, anchors, kern, fkb);
    hipLaunchKernelGGL(kB_gemm, dim3(MPAD/64), dim3(256), 0, stream,
                       fkb, Wb, out, psum, psq);
    hipLaunchKernelGGL(k2_stats, dim3(COUT), dim3(256), 0, stream, psum, psq, stats);
    hipLaunchKernelGGL(k3_norm, dim3(PA/1024, COUT), dim3(256), 0, stream, out, stats);
}

// Round 6
// 102.203 us; speedup vs baseline: 3.7356x; 3.7356x over previous
//
#include <hip/hip_runtime.h>

#define CIN  32
#define COUT 64
#define PP   1024
#define NN   24
#define NA   60
#define KS   4
#define PA   (PP*NA)          // 61440
#define CK   (CIN*KS)         // 128
#define FKLD 136              // padded LDS row stride in shorts (272 B)
constexpr float SIGMA_INV = 12.5f;   // 1/0.08
constexpr float EPS = 1e-5f;

typedef __attribute__((ext_vector_type(8))) short short8;
typedef __attribute__((ext_vector_type(4))) float floatx4;

__device__ inline unsigned f2bf1(float f) {   // RTNE to bf16, as unsigned
    unsigned u = __float_as_uint(f);
    return (u + 0x7fffu + ((u >> 16) & 1u)) >> 16;
}
__device__ inline unsigned packbf(float lo, float hi) {
    return f2bf1(lo) | (f2bf1(hi) << 16);
}

// ---------------- k1: fused gather + conv + MFMA GEMM + partial sums ----------------
__global__ __launch_bounds__(256, 4) void k1_fused(
    const float* __restrict__ xyz,       // [3,P]
    const float* __restrict__ feats,     // [CIN,P,NA]  (original layout, no transpose)
    const int*   __restrict__ inter_idx, // [P,NN]
    const float* __restrict__ anchors,   // [NA,3,3]
    const float* __restrict__ kern,      // [KS,3]
    const float* __restrict__ W,         // [COUT,CK]
    float* __restrict__ out,             // [COUT,PA]  pre-norm
    float* __restrict__ psum,            // [COUT,PP]
    float* __restrict__ psq)             // [COUT,PP]
{
    const int p      = blockIdx.x;
    const int tid    = threadIdx.x;
    const int g      = tid >> 6;          // wave 0..3 -> channels g*8..g*8+7, d-rows g*16..
    const int l      = tid & 63;
    const int lane15 = l & 15;
    const int quad   = l >> 4;
    const bool valid = (l < NA);
    const int  a     = valid ? l : (NA - 1);

    __shared__ float4 s_rel[NN];
    __shared__ int    s_idx[NN];
    __shared__ unsigned short s_fk[64 * FKLD];   // 17408 B

    // ---- phase A: neighbor relative coords ----
    if (tid < NN) {
        int j = inter_idx[p * NN + tid];
        s_idx[tid] = j;
        float rx = xyz[j]          - xyz[p];
        float ry = xyz[PP + j]     - xyz[PP + p];
        float rz = xyz[2 * PP + j] - xyz[2 * PP + p];
        s_rel[tid] = make_float4(rx, ry, rz, rx * rx + ry * ry + rz * rz);
    }

    // ---- phase B: per-thread rotated-kernel constants for anchor a ----
    float Cw[KS], Rx[KS], Ry[KS], Rz[KS];
    {
        const float* A = anchors + a * 9;
        float a00 = A[0], a01 = A[1], a02 = A[2];
        float a10 = A[3], a11 = A[4], a12 = A[5];
        float a20 = A[6], a21 = A[7], a22 = A[8];
        #pragma unroll
        for (int k = 0; k < KS; ++k) {
            float kx = kern[k * 3 + 0], ky = kern[k * 3 + 1], kz = kern[k * 3 + 2];
            float r0 = a00 * kx + a01 * ky + a02 * kz;
            float r1 = a10 * kx + a11 * ky + a12 * kz;
            float r2 = a20 * kx + a21 * ky + a22 * kz;
            Cw[k] = 1.0f - SIGMA_INV * (r0 * r0 + r1 * r1 + r2 * r2);
            Rx[k] = 2.0f * SIGMA_INV * r0;
            Ry[k] = 2.0f * SIGMA_INV * r1;
            Rz[k] = 2.0f * SIGMA_INV * r2;
        }
    }
    __syncthreads();

    // ---- phase D: fk[c,k] accumulation; gather is lane-coalesced (a = lane) ----
    float acc[8][KS];
    #pragma unroll
    for (int c = 0; c < 8; ++c)
        #pragma unroll
        for (int k = 0; k < KS; ++k) acc[c][k] = 0.0f;

    #pragma unroll 4
    for (int n = 0; n < NN; ++n) {
        float4 rel = s_rel[n];
        int j = s_idx[n];
        const float* fb = feats + (size_t)(g * 8) * PA + (size_t)j * NA + a;
        float f[8];
        #pragma unroll
        for (int c = 0; c < 8; ++c)
            f[c] = fb[(size_t)c * PA];     // 60 consecutive lanes -> 240B coalesced
        float tb = -SIGMA_INV * rel.w;
        float w[KS];
        #pragma unroll
        for (int k = 0; k < KS; ++k) {
            float v = Cw[k] + tb;
            v = fmaf(rel.x, Rx[k], v);
            v = fmaf(rel.y, Ry[k], v);
            v = fmaf(rel.z, Rz[k], v);
            w[k] = v > 0.0f ? v : 0.0f;
        }
        #pragma unroll
        for (int c = 0; c < 8; ++c)
            #pragma unroll
            for (int k = 0; k < KS; ++k)
                acc[c][k] = fmaf(f[c], w[k], acc[c][k]);
    }

    // ---- pack to bf16, stage in LDS: s_fk[row=a][col=ck] ----
    {
        unsigned pk[16];
        #pragma unroll
        for (int c = 0; c < 8; ++c) {
            pk[c * 2 + 0] = valid ? packbf(acc[c][0], acc[c][1]) : 0u;
            pk[c * 2 + 1] = valid ? packbf(acc[c][2], acc[c][3]) : 0u;
        }
        uint4* dst = (uint4*)&s_fk[(size_t)l * FKLD + g * 32];
        dst[0] = make_uint4(pk[0],  pk[1],  pk[2],  pk[3]);
        dst[1] = make_uint4(pk[4],  pk[5],  pk[6],  pk[7]);
        dst[2] = make_uint4(pk[8],  pk[9],  pk[10], pk[11]);
        dst[3] = make_uint4(pk[12], pk[13], pk[14], pk[15]);
    }

    // ---- W rows -> bf16 A-fragments (registers, layout = round-4 kB, verified) ----
    short8 afrag[4];
    {
        const float* wbase = W + (size_t)(g * 16 + lane15) * CK + quad * 8;
        #pragma unroll
        for (int ks = 0; ks < 4; ++ks) {
            float4 w0 = *(const float4*)(wbase + ks * 32);
            float4 w1 = *(const float4*)(wbase + ks * 32 + 4);
            union { short8 s; unsigned u[4]; } pa;
            pa.u[0] = packbf(w0.x, w0.y);
            pa.u[1] = packbf(w0.z, w0.w);
            pa.u[2] = packbf(w1.x, w1.y);
            pa.u[3] = packbf(w1.z, w1.w);
            afrag[ks] = pa.s;
        }
    }

    __syncthreads();

    // ---- phase E: MFMA  C[d, a] = sum_ck W[d,ck] * fk[a,ck] ----
    floatx4 cacc[4];
    #pragma unroll
    for (int t = 0; t < 4; ++t) cacc[t] = (floatx4){0.f, 0.f, 0.f, 0.f};

    #pragma unroll
    for (int ks = 0; ks < 4; ++ks) {
        #pragma unroll
        for (int t = 0; t < 4; ++t) {
            short8 bfrag = *(const short8*)&s_fk[(size_t)(t * 16 + lane15) * FKLD + ks * 32 + quad * 8];
            cacc[t] = __builtin_amdgcn_mfma_f32_16x16x32_bf16(afrag[ks], bfrag, cacc[t], 0, 0, 0);
        }
    }

    // ---- epilogue: store pre-norm out + per-(d,p) partial sums ----
    const int d0 = g * 16;
    float ssum[4] = {0.f, 0.f, 0.f, 0.f}, ssq[4] = {0.f, 0.f, 0.f, 0.f};
    #pragma unroll
    for (int t = 0; t < 4; ++t) {
        int acol = t * 16 + lane15;
        bool vcol = acol < NA;
        #pragma unroll
        for (int r = 0; r < 4; ++r) {
            float v = cacc[t][r];
            int d = d0 + quad * 4 + r;
            if (vcol) out[(size_t)d * PA + (size_t)p * NA + acol] = v;
            ssum[r] += v;   // padded cols are exact zeros
            ssq[r]  += v * v;
        }
    }
    #pragma unroll
    for (int r = 0; r < 4; ++r) {
        float ss = ssum[r], qq = ssq[r];
        #pragma unroll
        for (int off = 8; off; off >>= 1) {
            ss += __shfl_down(ss, off, 16);
            qq += __shfl_down(qq, off, 16);
        }
        if (lane15 == 0) {
            int d = d0 + quad * 4 + r;
            psum[d * PP + p] = ss;
            psq [d * PP + p] = qq;
        }
    }
}

// ---------------- k3: redundant per-channel stats + normalize + relu ----------------
// grid (60, 64): blockIdx.y = d, blockIdx.x = chunk of 1024 elements
__global__ __launch_bounds__(256) void k3_norm(
    const float* __restrict__ psum, const float* __restrict__ psq,
    float* __restrict__ out)
{
    const int d   = blockIdx.y;
    const int tid = threadIdx.x;

    // redundant reduction of this channel's 1024 partials (8 KB, L2-hot)
    float4 ps = ((const float4*)(psum + d * PP))[tid];
    float4 qs = ((const float4*)(psq  + d * PP))[tid];
    float s = ps.x + ps.y + ps.z + ps.w;
    float q = qs.x + qs.y + qs.z + qs.w;
    #pragma unroll
    for (int off = 32; off; off >>= 1) {
        s += __shfl_down(s, off, 64);
        q += __shfl_down(q, off, 64);
    }
    __shared__ float sred[8];
    __shared__ float s_mu, s_rs;
    int w = tid >> 6;
    if ((tid & 63) == 0) { sred[w] = s; sred[4 + w] = q; }
    __syncthreads();
    if (tid == 0) {
        float S = sred[0] + sred[1] + sred[2] + sred[3];
        float Q = sred[4] + sred[5] + sred[6] + sred[7];
        const float inv = 1.0f / (float)PA;
        float mu  = S * inv;
        float var = Q * inv - mu * mu;
        s_mu = mu;
        s_rs = rsqrtf(var + EPS);
    }
    __syncthreads();
    const float mu = s_mu, rs = s_rs;

    // normalize this block's 1024-element chunk (float4)
    size_t base = (size_t)d * PA + (size_t)blockIdx.x * 1024 + tid * 4;
    float4* po = (float4*)(out + base);
    float4 v = *po;
    v.x = fmaxf((v.x - mu) * rs, 0.f);
    v.y = fmaxf((v.y - mu) * rs, 0.f);
    v.z = fmaxf((v.z - mu) * rs, 0.f);
    v.w = fmaxf((v.w - mu) * rs, 0.f);
    *po = v;
}

extern "C" void kernel_launch(void* const* d_in, const int* in_sizes, int n_in,
                              void* d_out, int out_size, void* d_ws, size_t ws_size,
                              hipStream_t stream) {
    const float* xyz     = (const float*)d_in[0];
    const float* feats   = (const float*)d_in[1];
    const int*   idx     = (const int*)d_in[2];
    const float* anchors = (const float*)d_in[3];
    const float* kern    = (const float*)d_in[4];
    const float* W       = (const float*)d_in[5];
    float* out = (float*)d_out;

    float* ws   = (float*)d_ws;
    float* psum = ws;                 // 65,536 f
    float* psq  = psum + COUT * PP;   // 65,536 f

    hipLaunchKernelGGL(k1_fused, dim3(PP), dim3(256), 0, stream,
                       xyz, feats, idx, anchors, kern, W, out, psum, psq);
    hipLaunchKernelGGL(k3_norm, dim3(PA / 1024, COUT), dim3(256), 0, stream,
                       psum, psq, out);
}